// Round 14
// baseline (172.847 us; speedup 1.0000x reference)
//
#include <hip/hip_runtime.h>
#include <math.h>

// MoE gate, round 14: gemm rewritten with counted-vmcnt 3-buffer pipeline
// (T4: vmcnt(4) per body, never 0 until the tail; raw s_barrier + sched_barrier).
// R13 showed __syncthreads' vmcnt(0) drained the same-body prefetch -> each body
// paid full HBM latency serially. Staging remapped: threads 0-447 issue exactly
// 4 cp16/body (wave-uniform), wave 7 issues none. epi/fixup/pack/aux unchanged.

#define T_TOKENS 16384
#define HID      2048
#define NEXP     160
#define NGRP     8
#define EPG      20
#define KGRP     3
#define KTOP     6

#define BT     64
#define NBLK   (T_TOKENS / BT)   // 256
#define NBODY  64                // K bodies of 32
#define ABY    8192              // A per body: 64 rows x 128B
#define BBY    20480             // B per body
#define BUF    28672             // ABY + BBY
#define LPAD   68

typedef __attribute__((ext_vector_type(8))) short short8;
typedef __attribute__((ext_vector_type(4))) float f32x4;
typedef __attribute__((ext_vector_type(4))) unsigned int uint4v;

union U4S8 { uint4v u; short8 s; float4 f; };

__device__ __forceinline__ unsigned short f2bf(float f) {
    unsigned u = __float_as_uint(f);
    return (unsigned short)((u + 0x7FFFu + ((u >> 16) & 1u)) >> 16);
}
__device__ __forceinline__ float bf2f(unsigned short s) {
    return __uint_as_float(((unsigned)s) << 16);
}
__device__ __forceinline__ unsigned cvtpk(float a, float b) {
    unsigned r;
    asm volatile("v_cvt_pk_bf16_f32 %0, %1, %2" : "=v"(r) : "v"(a), "v"(b));
    return r;
}
__device__ __forceinline__ float lo16(unsigned u) { return __uint_as_float(u << 16); }
__device__ __forceinline__ float hi16(unsigned u) { return __uint_as_float(u & 0xFFFF0000u); }

__device__ __forceinline__ void cp16(char* lds, const float* g) {
    __builtin_amdgcn_global_load_lds(
        (const __attribute__((address_space(1))) unsigned int*)g,
        (__attribute__((address_space(3))) unsigned int*)lds, 16, 0, 0);
}

// ---- pack W: [s=0..63][nt=0..9][plane hi/lo][lane][8] ------------------------
__global__ __launch_bounds__(256)
void pack_w(const float* __restrict__ W, short* __restrict__ wpk)
{
    const int idx = blockIdx.x * 256 + threadIdx.x;   // 160*256
    const int e  = idx >> 8;
    const int kc = idx & 255;
    const int k0 = kc * 8;
    const float* src = W + (size_t)e * HID + k0;
    float x[8];
    *(float4*)&x[0] = *(const float4*)src;
    *(float4*)&x[4] = *(const float4*)(src + 4);
    short8 h, l;
#pragma unroll
    for (int j = 0; j < 8; ++j) {
        unsigned short hb = f2bf(x[j]);
        h[j] = (short)hb;
        l[j] = (short)f2bf(x[j] - bf2f(hb));
    }
    const int s    = kc >> 2;            // 32-K body
    const int kg   = kc & 3;
    const int lane = kg * 16 + (e & 15);
    const int nt   = e >> 4;
    const size_t base = (size_t)((s * 10 + nt) * 2) * 1024 + (size_t)lane * 16;
    *(short8*)((char*)wpk + base)        = h;
    *(short8*)((char*)wpk + base + 1024) = l;
}

// ---- GEMM: counted-vmcnt 3-buffer pipeline; logits -> global [NBLK][160][64] --
__global__ __launch_bounds__(512, 1)
void moe_gemm(const float* __restrict__ X, const short* __restrict__ wpk,
              float* __restrict__ glog)
{
    __shared__ __align__(16) char smem[3 * BUF];   // 86016 B

    const int tid  = threadIdx.x;
    const int lane = tid & 63;
    const int wave = tid >> 6;
    const int tokgrp = wave >> 1;        // 0..3
    const int ns     = wave & 1;         // 0..1
    const int tokBase = blockIdx.x * BT;
    const char* wpkc = (const char*)wpk;

    // ---- staging assignment: threads 0..447, 4 chunks each (wave-uniform) ----
    // chunk space: A = 512 chunks (16B), B = 1280 chunks. i = t + j*448.
    // j0: A[t].  j1: t<64 -> A[448+t], else B[t-64].  j2: B[t+384].  j3: B[t+832].
    const int t = tid;
    const char* sp0 = (const char*)(X + (size_t)(tokBase + (t >> 3)) * HID
                                      + (((t & 7) ^ ((t >> 3) & 7)) << 2));
    const int d0 = t * 16;
    const char* sp1; int st1, d1;
    if (t < 64) {
        sp1 = (const char*)(X + (size_t)(tokBase + 56 + (t >> 3)) * HID
                              + (((t & 7) ^ ((t >> 3) & 7)) << 2));
        st1 = 128; d1 = (448 + t) * 16;
    } else {
        sp1 = wpkc + (size_t)(t - 64) * 16; st1 = BBY; d1 = ABY + (t - 64) * 16;
    }
    const char* sp2 = wpkc + (size_t)(t + 384) * 16; const int d2 = ABY + (t + 384) * 16;
    const char* sp3 = wpkc + (size_t)(t + 832) * 16; const int d3 = ABY + (t + 832) * 16;

    // fragment addresses
    const int lr = lane & 15;
    const int kg = (lane >> 4) & 3;
    const int aoff0 = (tokgrp * 16 + lr) * 128 + (((kg * 2    ) ^ (lr & 7)) << 4);
    const int aoff1 = (tokgrp * 16 + lr) * 128 + (((kg * 2 + 1) ^ (lr & 7)) << 4);
    const int boff  = ABY + ns * 10240 + lane * 16;

    f32x4 acc[5];
#pragma unroll
    for (int n = 0; n < 5; ++n) acc[n] = (f32x4){0.f, 0.f, 0.f, 0.f};

#define STG(BI, S) if (t < 448) {                                        \
    char* b_ = smem + (BI) * BUF;                                        \
    cp16(b_ + d0, (const float*)(sp0 + (size_t)(S) * 128));              \
    cp16(b_ + d1, (const float*)(sp1 + (size_t)(S) * st1));              \
    cp16(b_ + d2, (const float*)(sp2 + (size_t)(S) * BBY));              \
    cp16(b_ + d3, (const float*)(sp3 + (size_t)(S) * BBY)); }

    // prologue: bodies 0,1 staged; wait for body 0 only (body 1 stays in flight)
    STG(0, 0)
    STG(1, 1)
    asm volatile("s_waitcnt vmcnt(4)" ::: "memory");
    __builtin_amdgcn_s_barrier();
    __builtin_amdgcn_sched_barrier(0);

#pragma unroll 1
    for (int s = 0; s < NBODY; ++s) {
        if (s + 2 < NBODY) STG((s + 2) % 3, s + 2)
        const char* ab = smem + (s % 3) * BUF;

        U4S8 af0, af1, ah, al;
        af0.f = *(const float4*)(ab + aoff0);
        af1.f = *(const float4*)(ab + aoff1);
        unsigned ph0 = cvtpk(af0.f.x, af0.f.y), ph1 = cvtpk(af0.f.z, af0.f.w);
        unsigned ph2 = cvtpk(af1.f.x, af1.f.y), ph3 = cvtpk(af1.f.z, af1.f.w);
        float l0 = af0.f.x - lo16(ph0), l1 = af0.f.y - hi16(ph0);
        float l2 = af0.f.z - lo16(ph1), l3 = af0.f.w - hi16(ph1);
        float l4 = af1.f.x - lo16(ph2), l5 = af1.f.y - hi16(ph2);
        float l6 = af1.f.z - lo16(ph3), l7 = af1.f.w - hi16(ph3);
        ah.u[0] = ph0; ah.u[1] = ph1; ah.u[2] = ph2; ah.u[3] = ph3;
        al.u[0] = cvtpk(l0, l1); al.u[1] = cvtpk(l2, l3);
        al.u[2] = cvtpk(l4, l5); al.u[3] = cvtpk(l6, l7);

#pragma unroll
        for (int nt = 0; nt < 5; ++nt) {
            U4S8 bh, bl;
            bh.u = *(const uint4v*)(ab + boff + nt * 2048);
            bl.u = *(const uint4v*)(ab + boff + nt * 2048 + 1024);
            acc[nt] = __builtin_amdgcn_mfma_f32_16x16x32_bf16(ah.s, bh.s, acc[nt], 0, 0, 0);
            acc[nt] = __builtin_amdgcn_mfma_f32_16x16x32_bf16(ah.s, bl.s, acc[nt], 0, 0, 0);
            acc[nt] = __builtin_amdgcn_mfma_f32_16x16x32_bf16(al.s, bh.s, acc[nt], 0, 0, 0);
        }

        // counted wait: STG(s+1) complete, STG(s+2)'s 4 loads stay in flight.
        if (s < NBODY - 2)       asm volatile("s_waitcnt vmcnt(4)" ::: "memory");
        else if (s == NBODY - 2) asm volatile("s_waitcnt vmcnt(0)" ::: "memory");
        if (s < NBODY - 1) {
            __builtin_amdgcn_s_barrier();
            __builtin_amdgcn_sched_barrier(0);
        }
    }
#undef STG

    float* gb = glog + (size_t)blockIdx.x * NEXP * BT;
#pragma unroll
    for (int nt = 0; nt < 5; ++nt) {
        const int e = ns * 80 + nt * 16 + lr;
        *(f32x4*)(gb + e * BT + tokgrp * 16 + kg * 4) = acc[nt];
    }
}

// ---- epilogue: selection + Pi/hist partials ----------------------------------
__global__ __launch_bounds__(512, 2)
void moe_epi(const float* __restrict__ glog, float* __restrict__ out,
             float* __restrict__ piPart, unsigned int* __restrict__ histPart,
             unsigned int* __restrict__ flagCnt, unsigned int* __restrict__ flagList)
{
    __shared__ __align__(16) float pL[NEXP * LPAD];   // 43520 B
    __shared__ __align__(16) float m_arr[BT];
    __shared__ __align__(16) float invd_arr[BT];
    __shared__ unsigned histL[NEXP];

    const int tid  = threadIdx.x;
    const int lane = tid & 63;
    const int tokBase = blockIdx.x * BT;
    const float* gb = glog + (size_t)blockIdx.x * NEXP * BT;

#pragma unroll
    for (int j = 0; j < 5; ++j) {
        const int i = tid + j * 512;
        const int e = i >> 4, t4 = (i & 15) << 2;
        const float4 v = *(const float4*)(gb + e * BT + t4);
        *(float4*)&pL[e * LPAD + t4] = v;
    }
    if (tid < NEXP) histL[tid] = 0;
    __syncthreads();

    {
        const int t  = tid >> 3;
        const int gl = tid & 7;
        const int lbase = lane & 0x38;

        float mg_ = pL[(gl * EPG) * LPAD + t];
#pragma unroll
        for (int j = 1; j < EPG; ++j) mg_ = fmaxf(mg_, pL[(gl * EPG + j) * LPAD + t]);

        float gv[8];
#pragma unroll
        for (int gi = 0; gi < 8; ++gi) gv[gi] = __shfl(mg_, lbase + gi);

        float best = -1e30f; int bi = 0;
#pragma unroll
        for (int gi = 0; gi < NGRP; ++gi) if (gv[gi] > best) { best = gv[gi]; bi = gi; }
        const int sel0 = bi; int gmask = 1 << bi;
        best = -1e30f; bi = 0;
#pragma unroll
        for (int gi = 0; gi < NGRP; ++gi)
            if (!((gmask >> gi) & 1) && gv[gi] > best) { best = gv[gi]; bi = gi; }
        const int sel1 = bi; gmask |= 1 << bi;
        best = -1e30f; bi = 0;
#pragma unroll
        for (int gi = 0; gi < NGRP; ++gi)
            if (!((gmask >> gi) & 1) && gv[gi] > best) { best = gv[gi]; bi = gi; }
        const int sel2 = bi; gmask |= 1 << bi;
        const float g3v = best;
        float g4v = -1e30f;
#pragma unroll
        for (int gi = 0; gi < NGRP; ++gi)
            if (!((gmask >> gi) & 1)) g4v = fmaxf(g4v, gv[gi]);
        float mall = gv[0];
#pragma unroll
        for (int gi = 1; gi < NGRP; ++gi) mall = fmaxf(mall, gv[gi]);

        float dsum = 0.f;
#pragma unroll
        for (int j = 0; j < EPG; ++j)
            dsum += expf(pL[(gl * EPG + j) * LPAD + t] - mall);
        dsum += __shfl_xor(dsum, 1);
        dsum += __shfl_xor(dsum, 2);
        dsum += __shfl_xor(dsum, 4);
        const float invd = 1.0f / dsum;

        float cvv[8]; int ce[8];
#pragma unroll
        for (int c = 0; c < 8; ++c) {
            const int i = gl + 8 * c;
            if (i < 60) {
                const int sgrp = (i >= 40) ? sel2 : ((i >= 20) ? sel1 : sel0);
                const int e = sgrp * EPG + (i - ((i >= 40) ? 40 : ((i >= 20) ? 20 : 0)));
                ce[c] = e;
                cvv[c] = pL[e * LPAD + t];
            } else { ce[c] = 999; cvv[c] = -1e30f; }
        }

        int ch0, ch1, ch2, ch3, ch4, ch5;
        float cv0, cv1, cv2, cv3, cv4, cv5, cv6;
#pragma unroll
        for (int p = 0; p < 7; ++p) {
            float bv = -1e30f; int be = 999;
#pragma unroll
            for (int c = 0; c < 8; ++c)
                if (cvv[c] > bv || (cvv[c] == bv && ce[c] < be)) { bv = cvv[c]; be = ce[c]; }
#pragma unroll
            for (int off = 1; off < 8; off <<= 1) {
                const float ov = __shfl_xor(bv, off);
                const int   oe = __shfl_xor(be, off);
                if (ov > bv || (ov == bv && oe < be)) { bv = ov; be = oe; }
            }
#pragma unroll
            for (int c = 0; c < 8; ++c) if (ce[c] == be) cvv[c] = -1e30f;
            if (p == 0) { ch0 = be; cv0 = bv; }
            else if (p == 1) { ch1 = be; cv1 = bv; }
            else if (p == 2) { ch2 = be; cv2 = bv; }
            else if (p == 3) { ch3 = be; cv3 = bv; }
            else if (p == 4) { ch4 = be; cv4 = bv; }
            else if (p == 5) { ch5 = be; cv5 = bv; }
            else { cv6 = bv; }
        }

        if (gl == 0) {
            const int gt = tokBase + t;
            out[(size_t)gt * KTOP + 0] = (float)ch0;
            out[(size_t)gt * KTOP + 1] = (float)ch1;
            out[(size_t)gt * KTOP + 2] = (float)ch2;
            out[(size_t)gt * KTOP + 3] = (float)ch3;
            out[(size_t)gt * KTOP + 4] = (float)ch4;
            out[(size_t)gt * KTOP + 5] = (float)ch5;
            float* wo = out + (size_t)T_TOKENS * KTOP + (size_t)gt * KTOP;
            wo[0] = expf(cv0 - mall) * invd * 16.0f;
            wo[1] = expf(cv1 - mall) * invd * 16.0f;
            wo[2] = expf(cv2 - mall) * invd * 16.0f;
            wo[3] = expf(cv3 - mall) * invd * 16.0f;
            wo[4] = expf(cv4 - mall) * invd * 16.0f;
            wo[5] = expf(cv5 - mall) * invd * 16.0f;
            atomicAdd(&histL[ch0], 1u); atomicAdd(&histL[ch1], 1u);
            atomicAdd(&histL[ch2], 1u); atomicAdd(&histL[ch3], 1u);
            atomicAdd(&histL[ch4], 1u); atomicAdd(&histL[ch5], 1u);
            m_arr[t] = mall; invd_arr[t] = invd;
            float mg2 = g3v - g4v;
            mg2 = fminf(mg2, cv0 - cv1); mg2 = fminf(mg2, cv1 - cv2);
            mg2 = fminf(mg2, cv2 - cv3); mg2 = fminf(mg2, cv3 - cv4);
            mg2 = fminf(mg2, cv4 - cv5); mg2 = fminf(mg2, cv5 - cv6);
            if (mg2 < 1e-4f) {
                const unsigned pos = atomicAdd(flagCnt, 1u);
                flagList[pos] = (unsigned)gt;
            }
        }
    }
    __syncthreads();

    if (tid < NEXP) {
        const float* Le = pL + tid * LPAD;
        float s = 0.f;
#pragma unroll 4
        for (int t0 = 0; t0 < BT; t0 += 4) {
            const float4 lv = *(const float4*)(Le + t0);
            const float4 mv = *(const float4*)(m_arr + t0);
            const float4 iv = *(const float4*)(invd_arr + t0);
            s += expf(lv.x - mv.x) * iv.x;
            s += expf(lv.y - mv.y) * iv.y;
            s += expf(lv.z - mv.z) * iv.z;
            s += expf(lv.w - mv.w) * iv.w;
        }
        piPart[(size_t)tid * NBLK + blockIdx.x]   = s;
        histPart[(size_t)tid * NBLK + blockIdx.x] = histL[tid];
    }
}

// ---- fp64 fixup: 16 waves/block, hoisted loads, 10 experts/wave ---------------
__global__ __launch_bounds__(1024)
void moe_gate_fixup(const float* __restrict__ X, const float* __restrict__ W,
                    float* __restrict__ out, const unsigned int* __restrict__ flagCnt,
                    const unsigned int* __restrict__ flagList)
{
    __shared__ float xs[HID];
    __shared__ double ld[NEXP];
    const int nflag = (int)*flagCnt;
    const int tid = threadIdx.x;
    const int wv = tid >> 6, ln = tid & 63;   // 16 waves

    for (int i = blockIdx.x; i < nflag; i += gridDim.x) {
        const int t = (int)flagList[i];
        __syncthreads();
        for (int k = tid; k < HID / 4; k += 1024)
            ((float4*)xs)[k] = ((const float4*)(X + (size_t)t * HID))[k];
        __syncthreads();

#pragma unroll 1
        for (int e = wv; e < NEXP; e += 16) {
            const float* wr = W + (size_t)e * HID + ln * 4;
            const float* xp = xs + ln * 4;
            float4 w4[8];
#pragma unroll
            for (int j = 0; j < 8; ++j) w4[j] = *(const float4*)(wr + j * 256);
            double a0 = 0.0, a1 = 0.0;
#pragma unroll
            for (int j = 0; j < 8; ++j) {
                a0 = fma((double)xp[j * 256 + 0], (double)w4[j].x, a0);
                a1 = fma((double)xp[j * 256 + 1], (double)w4[j].y, a1);
                a0 = fma((double)xp[j * 256 + 2], (double)w4[j].z, a0);
                a1 = fma((double)xp[j * 256 + 3], (double)w4[j].w, a1);
            }
            double a = a0 + a1;
#pragma unroll
            for (int off = 32; off > 0; off >>= 1) a += __shfl_down(a, off);
            if (ln == 0) ld[e] = a;
        }
        __syncthreads();

        if (tid == 0) {
            double g[NGRP];
#pragma unroll
            for (int gi = 0; gi < NGRP; ++gi) {
                double mx = ld[gi * EPG];
                for (int j = 1; j < EPG; ++j) {
                    const double v = ld[gi * EPG + j];
                    if (v > mx) mx = v;
                }
                g[gi] = mx;
            }
            int gmask = 0;
#pragma unroll
            for (int p = 0; p < KGRP; ++p) {
                double best = -1.0e300; int bi = 0;
#pragma unroll
                for (int gi = 0; gi < NGRP; ++gi)
                    if (!((gmask >> gi) & 1) && g[gi] > best) { best = g[gi]; bi = gi; }
                gmask |= 1 << bi;
            }
            double mall = g[0];
#pragma unroll
            for (int gi = 1; gi < NGRP; ++gi) if (g[gi] > mall) mall = g[gi];
            float denom = 0.f;
            for (int e = 0; e < NEXP; ++e)
                denom += expf((float)(ld[e] - mall));
            const float invd = 1.0f / denom;

            int ch[KTOP];
            for (int p = 0; p < KTOP; ++p) {
                double best = -1.0e300; int bi = 0;
                for (int e = 0; e < NEXP; ++e) {
                    if (!((gmask >> (e / EPG)) & 1)) continue;
                    bool used = false;
#pragma unroll
                    for (int q = 0; q < KTOP; ++q)
                        if (q < p && ch[q] == e) used = true;
                    if (!used && ld[e] > best) { best = ld[e]; bi = e; }
                }
                ch[p] = bi;
                out[(size_t)t * KTOP + p] = (float)bi;
                out[(size_t)T_TOKENS * KTOP + (size_t)t * KTOP + p] =
                    expf((float)(best - mall)) * invd * 16.0f;
            }
        }
        __syncthreads();
    }
}

// ---- aux loss: reduce partials ----------------------------------------------
__global__ __launch_bounds__(256)
void moe_gate_aux(const float* __restrict__ piPart,
                  const unsigned int* __restrict__ histPart,
                  float* __restrict__ out)
{
    __shared__ double buf[NEXP];
    const int tid = threadIdx.x;
    if (tid < NEXP) {
        const float* pp = piPart + (size_t)tid * NBLK;
        const unsigned int* hp = histPart + (size_t)tid * NBLK;
        float s = 0.f;
        unsigned c = 0;
#pragma unroll 8
        for (int b = 0; b < NBLK; ++b) { s += pp[b]; c += hp[b]; }
        buf[tid] = (double)s * (double)c;
    }
    __syncthreads();
    if (tid == 0) {
        double s = 0.0;
        for (int e = 0; e < NEXP; ++e) s += buf[e];
        const double aux = s * (0.001 * (double)NEXP) /
                           ((double)T_TOKENS * (double)T_TOKENS * (double)KTOP);
        out[(size_t)T_TOKENS * KTOP * 2] = (float)aux;
    }
}

extern "C" void kernel_launch(void* const* d_in, const int* in_sizes, int n_in,
                              void* d_out, int out_size, void* d_ws, size_t ws_size,
                              hipStream_t stream)
{
    const float* X = (const float*)d_in[0];   // [16384, 2048]
    const float* W = (const float*)d_in[1];   // [160, 2048]
    float* out = (float*)d_out;               // [98304 idx][98304 wgt][1 aux]

    char* ws = (char*)d_ws;
    short* wpk = (short*)ws;                                    // 1,310,720 B
    float* glog = (float*)(ws + 1310720);                       // 10,485,760 B
    float* piPart = (float*)(ws + 11796480);                    // 163,840 B
    unsigned int* histPart = (unsigned int*)(ws + 11960320);    // 163,840 B
    unsigned int* flagCnt  = (unsigned int*)(ws + 12124160);    // 16 B
    unsigned int* flagList = (unsigned int*)(ws + 12124176);    // 64 KB

    hipMemsetAsync(flagCnt, 0, 16, stream);
    pack_w<<<160, 256, 0, stream>>>(W, wpk);
    moe_gemm<<<NBLK, 512, 0, stream>>>(X, wpk, glog);
    moe_epi<<<NBLK, 512, 0, stream>>>(glog, out, piPart, histPart, flagCnt, flagList);
    moe_gate_fixup<<<512, 1024, 0, stream>>>(X, W, out, flagCnt, flagList);
    moe_gate_aux<<<1, 256, 0, stream>>>(piPart, histPart, out);
}

// Round 15
// 156.258 us; speedup vs baseline: 1.1062x; 1.1062x over previous
//
#include <hip/hip_runtime.h>
#include <math.h>

// MoE gate, round 15: gemm staging switched from global_load_lds to REG-STAGING
// (global->reg->ds_write, HK/T14 pattern). R8/R10/R13/R14 all showed a constant
// ~100-130 cyc per global_load_lds instruction per CU (throughput-saturated DMA
// unit: 2 blocks/CU split the rate, counted-vmcnt didn't help). Plain loads
// pipeline deeply; ds_write_b128 ~12cyc. 2-phase BK=64, P/Q reg sets, counted
// vmcnt(7). Compute/epi/fixup/pack/aux byte-identical to round 14.

#define T_TOKENS 16384
#define HID      2048
#define NEXP     160
#define NGRP     8
#define EPG      20
#define KGRP     3
#define KTOP     6

#define BT     64
#define NBLK   (T_TOKENS / BT)   // 256
#define NBODY  32                // K bodies of 64
#define ABY    16384             // A per body: 64 rows x 256B
#define BBY    40960             // B per body
#define BUF    57344             // ABY + BBY
#define LPAD   68

typedef __attribute__((ext_vector_type(8))) short short8;
typedef __attribute__((ext_vector_type(4))) float f32x4;
typedef __attribute__((ext_vector_type(4))) unsigned int uint4v;

union U4S8 { uint4v u; short8 s; float4 f; };

__device__ __forceinline__ unsigned short f2bf(float f) {
    unsigned u = __float_as_uint(f);
    return (unsigned short)((u + 0x7FFFu + ((u >> 16) & 1u)) >> 16);
}
__device__ __forceinline__ float bf2f(unsigned short s) {
    return __uint_as_float(((unsigned)s) << 16);
}
__device__ __forceinline__ unsigned cvtpk(float a, float b) {
    unsigned r;
    asm volatile("v_cvt_pk_bf16_f32 %0, %1, %2" : "=v"(r) : "v"(a), "v"(b));
    return r;
}
__device__ __forceinline__ float lo16(unsigned u) { return __uint_as_float(u << 16); }
__device__ __forceinline__ float hi16(unsigned u) { return __uint_as_float(u & 0xFFFF0000u); }

// ---- pack W: [s=0..63][nt=0..9][plane hi/lo][lane][8] ------------------------
__global__ __launch_bounds__(256)
void pack_w(const float* __restrict__ W, short* __restrict__ wpk)
{
    const int idx = blockIdx.x * 256 + threadIdx.x;   // 160*256
    const int e  = idx >> 8;
    const int kc = idx & 255;
    const int k0 = kc * 8;
    const float* src = W + (size_t)e * HID + k0;
    float x[8];
    *(float4*)&x[0] = *(const float4*)src;
    *(float4*)&x[4] = *(const float4*)(src + 4);
    short8 h, l;
#pragma unroll
    for (int j = 0; j < 8; ++j) {
        unsigned short hb = f2bf(x[j]);
        h[j] = (short)hb;
        l[j] = (short)f2bf(x[j] - bf2f(hb));
    }
    const int s    = kc >> 2;            // 32-K step
    const int kg   = kc & 3;
    const int lane = kg * 16 + (e & 15);
    const int nt   = e >> 4;
    const size_t base = (size_t)((s * 10 + nt) * 2) * 1024 + (size_t)lane * 16;
    *(short8*)((char*)wpk + base)        = h;
    *(short8*)((char*)wpk + base + 1024) = l;
}

// ---- GEMM: reg-staged 2-phase pipeline; logits -> global [NBLK][160][64] -----
__global__ __launch_bounds__(512, 1)
void moe_gemm(const float* __restrict__ X, const short* __restrict__ wpk,
              float* __restrict__ glog)
{
    __shared__ __align__(16) char smem[2 * BUF];   // 114688 B

    const int tid  = threadIdx.x;
    const int lane = tid & 63;
    const int wave = tid >> 6;
    const int tokgrp = wave >> 1;        // 0..3
    const int ns     = wave & 1;         // 0..1
    const int tokBase = blockIdx.x * BT;
    const char* wpkc = (const char*)wpk;

    // staging: thread t covers A chunks {t, t+512}, B chunks {t+j*512, j=0..4}
    const int t = tid;
    const int r0 = t >> 4;
    const int g0 = (t & 15) ^ (r0 & 7);            // XOR-swizzled source chunk
    const float* xsrc0 = X + (size_t)(tokBase + r0) * HID + g0 * 4;
    const float* xsrc1 = X + (size_t)(tokBase + r0 + 32) * HID + g0 * 4;

    // fragment addresses
    const int lr = lane & 15;
    const int kg = (lane >> 4) & 3;
    const int rbase = (tokgrp * 16 + lr) * 256;
    const int a00 = rbase + (((kg * 2    ) ^ (lr & 7)) << 4);
    const int a01 = rbase + (((kg * 2 + 1) ^ (lr & 7)) << 4);
    const int bb0 = ABY + ns * 10240 + lane * 16;

    f32x4 acc[5];
#pragma unroll
    for (int n = 0; n < 5; ++n) acc[n] = (f32x4){0.f, 0.f, 0.f, 0.f};

    float4 Pa0, Pa1, Qa0, Qa1;
    uint4v Pb0, Pb1, Pb2, Pb3, Pb4, Qb0, Qb1, Qb2, Qb3, Qb4;

#define LOADR(SET, S) {                                                        \
    SET##a0 = *(const float4*)(xsrc0 + (size_t)(S) * 64);                      \
    SET##a1 = *(const float4*)(xsrc1 + (size_t)(S) * 64);                      \
    const char* wb_ = wpkc + (size_t)(S) * BBY + (size_t)t * 16;               \
    SET##b0 = *(const uint4v*)(wb_);                                           \
    SET##b1 = *(const uint4v*)(wb_ + 8192);                                    \
    SET##b2 = *(const uint4v*)(wb_ + 16384);                                   \
    SET##b3 = *(const uint4v*)(wb_ + 24576);                                   \
    SET##b4 = *(const uint4v*)(wb_ + 32768); }

#define WRITE(BI, SET) { char* b_ = smem + (BI) * BUF;                         \
    *(float4*)(b_ + t * 16)          = SET##a0;                                \
    *(float4*)(b_ + (t + 512) * 16)  = SET##a1;                                \
    char* bb_ = b_ + ABY + t * 16;                                             \
    *(uint4v*)(bb_)          = SET##b0;                                        \
    *(uint4v*)(bb_ + 8192)   = SET##b1;                                        \
    *(uint4v*)(bb_ + 16384)  = SET##b2;                                        \
    *(uint4v*)(bb_ + 24576)  = SET##b3;                                        \
    *(uint4v*)(bb_ + 32768)  = SET##b4; }

#define COMPUTE(BI) { const char* ab = smem + (BI) * BUF;                      \
    _Pragma("unroll") for (int ks = 0; ks < 2; ++ks) {                         \
        U4S8 af0, af1, ah, al;                                                 \
        af0.f = *(const float4*)(ab + a00 + ks * 128);                         \
        af1.f = *(const float4*)(ab + a01 + ks * 128);                         \
        unsigned ph0 = cvtpk(af0.f.x, af0.f.y), ph1 = cvtpk(af0.f.z, af0.f.w); \
        unsigned ph2 = cvtpk(af1.f.x, af1.f.y), ph3 = cvtpk(af1.f.z, af1.f.w); \
        float l0 = af0.f.x - lo16(ph0), l1 = af0.f.y - hi16(ph0);              \
        float l2 = af0.f.z - lo16(ph1), l3 = af0.f.w - hi16(ph1);              \
        float l4 = af1.f.x - lo16(ph2), l5 = af1.f.y - hi16(ph2);              \
        float l6 = af1.f.z - lo16(ph3), l7 = af1.f.w - hi16(ph3);              \
        ah.u[0] = ph0; ah.u[1] = ph1; ah.u[2] = ph2; ah.u[3] = ph3;            \
        al.u[0] = cvtpk(l0, l1); al.u[1] = cvtpk(l2, l3);                      \
        al.u[2] = cvtpk(l4, l5); al.u[3] = cvtpk(l6, l7);                      \
        _Pragma("unroll") for (int nt = 0; nt < 5; ++nt) {                     \
            U4S8 bh, bl;                                                       \
            bh.u = *(const uint4v*)(ab + bb0 + ks * 20480 + nt * 2048);        \
            bl.u = *(const uint4v*)(ab + bb0 + ks * 20480 + nt * 2048 + 1024); \
            acc[nt] = __builtin_amdgcn_mfma_f32_16x16x32_bf16(ah.s, bh.s, acc[nt], 0, 0, 0); \
            acc[nt] = __builtin_amdgcn_mfma_f32_16x16x32_bf16(ah.s, bl.s, acc[nt], 0, 0, 0); \
            acc[nt] = __builtin_amdgcn_mfma_f32_16x16x32_bf16(al.s, bh.s, acc[nt], 0, 0, 0); \
        } } }

#define FENCE() { asm volatile("s_waitcnt lgkmcnt(0)" ::: "memory");           \
    __builtin_amdgcn_s_barrier(); __builtin_amdgcn_sched_barrier(0); }

    // prologue: P<-body0, Q<-body1; wait P; write buf0; fence
    LOADR(P, 0)
    LOADR(Q, 1)
    asm volatile("s_waitcnt vmcnt(7)" ::: "memory");
    WRITE(0, P)
    FENCE()

    // BODY2(S0): even body S0 {load P<-S0+2, compute buf0, wait Q, write buf1},
    //            odd body S0+1 {load Q<-S0+3, compute buf1, wait P, write buf0}
#define BODY2(S0) {                                                            \
    if ((S0) + 2 < NBODY) LOADR(P, (S0) + 2)                                   \
    COMPUTE(0)                                                                 \
    if ((S0) < NBODY - 2) { asm volatile("s_waitcnt vmcnt(7)" ::: "memory"); } \
    else                  { asm volatile("s_waitcnt vmcnt(0)" ::: "memory"); } \
    WRITE(1, Q)                                                                \
    FENCE()                                                                    \
    if ((S0) + 3 < NBODY) LOADR(Q, (S0) + 3)                                   \
    COMPUTE(1)                                                                 \
    if ((S0) + 1 < NBODY - 1) {                                                \
        if ((S0) + 1 < NBODY - 2) { asm volatile("s_waitcnt vmcnt(7)" ::: "memory"); } \
        else                      { asm volatile("s_waitcnt vmcnt(0)" ::: "memory"); } \
        WRITE(0, P)                                                            \
        FENCE()                                                                \
    } }

    BODY2(0)  BODY2(2)  BODY2(4)  BODY2(6)
    BODY2(8)  BODY2(10) BODY2(12) BODY2(14)
    BODY2(16) BODY2(18) BODY2(20) BODY2(22)
    BODY2(24) BODY2(26) BODY2(28) BODY2(30)
#undef BODY2
#undef LOADR
#undef WRITE
#undef COMPUTE
#undef FENCE

    float* gb = glog + (size_t)blockIdx.x * NEXP * BT;
#pragma unroll
    for (int nt = 0; nt < 5; ++nt) {
        const int e = ns * 80 + nt * 16 + lr;
        *(f32x4*)(gb + e * BT + tokgrp * 16 + kg * 4) = acc[nt];
    }
}

// ---- epilogue: selection + Pi/hist partials ----------------------------------
__global__ __launch_bounds__(512, 2)
void moe_epi(const float* __restrict__ glog, float* __restrict__ out,
             float* __restrict__ piPart, unsigned int* __restrict__ histPart,
             unsigned int* __restrict__ flagCnt, unsigned int* __restrict__ flagList)
{
    __shared__ __align__(16) float pL[NEXP * LPAD];   // 43520 B
    __shared__ __align__(16) float m_arr[BT];
    __shared__ __align__(16) float invd_arr[BT];
    __shared__ unsigned histL[NEXP];

    const int tid  = threadIdx.x;
    const int lane = tid & 63;
    const int tokBase = blockIdx.x * BT;
    const float* gb = glog + (size_t)blockIdx.x * NEXP * BT;

#pragma unroll
    for (int j = 0; j < 5; ++j) {
        const int i = tid + j * 512;
        const int e = i >> 4, t4 = (i & 15) << 2;
        const float4 v = *(const float4*)(gb + e * BT + t4);
        *(float4*)&pL[e * LPAD + t4] = v;
    }
    if (tid < NEXP) histL[tid] = 0;
    __syncthreads();

    {
        const int t  = tid >> 3;
        const int gl = tid & 7;
        const int lbase = lane & 0x38;

        float mg_ = pL[(gl * EPG) * LPAD + t];
#pragma unroll
        for (int j = 1; j < EPG; ++j) mg_ = fmaxf(mg_, pL[(gl * EPG + j) * LPAD + t]);

        float gv[8];
#pragma unroll
        for (int gi = 0; gi < 8; ++gi) gv[gi] = __shfl(mg_, lbase + gi);

        float best = -1e30f; int bi = 0;
#pragma unroll
        for (int gi = 0; gi < NGRP; ++gi) if (gv[gi] > best) { best = gv[gi]; bi = gi; }
        const int sel0 = bi; int gmask = 1 << bi;
        best = -1e30f; bi = 0;
#pragma unroll
        for (int gi = 0; gi < NGRP; ++gi)
            if (!((gmask >> gi) & 1) && gv[gi] > best) { best = gv[gi]; bi = gi; }
        const int sel1 = bi; gmask |= 1 << bi;
        best = -1e30f; bi = 0;
#pragma unroll
        for (int gi = 0; gi < NGRP; ++gi)
            if (!((gmask >> gi) & 1) && gv[gi] > best) { best = gv[gi]; bi = gi; }
        const int sel2 = bi; gmask |= 1 << bi;
        const float g3v = best;
        float g4v = -1e30f;
#pragma unroll
        for (int gi = 0; gi < NGRP; ++gi)
            if (!((gmask >> gi) & 1)) g4v = fmaxf(g4v, gv[gi]);
        float mall = gv[0];
#pragma unroll
        for (int gi = 1; gi < NGRP; ++gi) mall = fmaxf(mall, gv[gi]);

        float dsum = 0.f;
#pragma unroll
        for (int j = 0; j < EPG; ++j)
            dsum += expf(pL[(gl * EPG + j) * LPAD + t] - mall);
        dsum += __shfl_xor(dsum, 1);
        dsum += __shfl_xor(dsum, 2);
        dsum += __shfl_xor(dsum, 4);
        const float invd = 1.0f / dsum;

        float cvv[8]; int ce[8];
#pragma unroll
        for (int c = 0; c < 8; ++c) {
            const int i = gl + 8 * c;
            if (i < 60) {
                const int sgrp = (i >= 40) ? sel2 : ((i >= 20) ? sel1 : sel0);
                const int e = sgrp * EPG + (i - ((i >= 40) ? 40 : ((i >= 20) ? 20 : 0)));
                ce[c] = e;
                cvv[c] = pL[e * LPAD + t];
            } else { ce[c] = 999; cvv[c] = -1e30f; }
        }

        int ch0, ch1, ch2, ch3, ch4, ch5;
        float cv0, cv1, cv2, cv3, cv4, cv5, cv6;
#pragma unroll
        for (int p = 0; p < 7; ++p) {
            float bv = -1e30f; int be = 999;
#pragma unroll
            for (int c = 0; c < 8; ++c)
                if (cvv[c] > bv || (cvv[c] == bv && ce[c] < be)) { bv = cvv[c]; be = ce[c]; }
#pragma unroll
            for (int off = 1; off < 8; off <<= 1) {
                const float ov = __shfl_xor(bv, off);
                const int   oe = __shfl_xor(be, off);
                if (ov > bv || (ov == bv && oe < be)) { bv = ov; be = oe; }
            }
#pragma unroll
            for (int c = 0; c < 8; ++c) if (ce[c] == be) cvv[c] = -1e30f;
            if (p == 0) { ch0 = be; cv0 = bv; }
            else if (p == 1) { ch1 = be; cv1 = bv; }
            else if (p == 2) { ch2 = be; cv2 = bv; }
            else if (p == 3) { ch3 = be; cv3 = bv; }
            else if (p == 4) { ch4 = be; cv4 = bv; }
            else if (p == 5) { ch5 = be; cv5 = bv; }
            else { cv6 = bv; }
        }

        if (gl == 0) {
            const int gt = tokBase + t;
            out[(size_t)gt * KTOP + 0] = (float)ch0;
            out[(size_t)gt * KTOP + 1] = (float)ch1;
            out[(size_t)gt * KTOP + 2] = (float)ch2;
            out[(size_t)gt * KTOP + 3] = (float)ch3;
            out[(size_t)gt * KTOP + 4] = (float)ch4;
            out[(size_t)gt * KTOP + 5] = (float)ch5;
            float* wo = out + (size_t)T_TOKENS * KTOP + (size_t)gt * KTOP;
            wo[0] = expf(cv0 - mall) * invd * 16.0f;
            wo[1] = expf(cv1 - mall) * invd * 16.0f;
            wo[2] = expf(cv2 - mall) * invd * 16.0f;
            wo[3] = expf(cv3 - mall) * invd * 16.0f;
            wo[4] = expf(cv4 - mall) * invd * 16.0f;
            wo[5] = expf(cv5 - mall) * invd * 16.0f;
            atomicAdd(&histL[ch0], 1u); atomicAdd(&histL[ch1], 1u);
            atomicAdd(&histL[ch2], 1u); atomicAdd(&histL[ch3], 1u);
            atomicAdd(&histL[ch4], 1u); atomicAdd(&histL[ch5], 1u);
            m_arr[t] = mall; invd_arr[t] = invd;
            float mg2 = g3v - g4v;
            mg2 = fminf(mg2, cv0 - cv1); mg2 = fminf(mg2, cv1 - cv2);
            mg2 = fminf(mg2, cv2 - cv3); mg2 = fminf(mg2, cv3 - cv4);
            mg2 = fminf(mg2, cv4 - cv5); mg2 = fminf(mg2, cv5 - cv6);
            if (mg2 < 1e-4f) {
                const unsigned pos = atomicAdd(flagCnt, 1u);
                flagList[pos] = (unsigned)gt;
            }
        }
    }
    __syncthreads();

    if (tid < NEXP) {
        const float* Le = pL + tid * LPAD;
        float s = 0.f;
#pragma unroll 4
        for (int t0 = 0; t0 < BT; t0 += 4) {
            const float4 lv = *(const float4*)(Le + t0);
            const float4 mv = *(const float4*)(m_arr + t0);
            const float4 iv = *(const float4*)(invd_arr + t0);
            s += expf(lv.x - mv.x) * iv.x;
            s += expf(lv.y - mv.y) * iv.y;
            s += expf(lv.z - mv.z) * iv.z;
            s += expf(lv.w - mv.w) * iv.w;
        }
        piPart[(size_t)tid * NBLK + blockIdx.x]   = s;
        histPart[(size_t)tid * NBLK + blockIdx.x] = histL[tid];
    }
}

// ---- fp64 fixup: 16 waves/block, hoisted loads, 10 experts/wave ---------------
__global__ __launch_bounds__(1024)
void moe_gate_fixup(const float* __restrict__ X, const float* __restrict__ W,
                    float* __restrict__ out, const unsigned int* __restrict__ flagCnt,
                    const unsigned int* __restrict__ flagList)
{
    __shared__ float xs[HID];
    __shared__ double ld[NEXP];
    const int nflag = (int)*flagCnt;
    const int tid = threadIdx.x;
    const int wv = tid >> 6, ln = tid & 63;   // 16 waves

    for (int i = blockIdx.x; i < nflag; i += gridDim.x) {
        const int t = (int)flagList[i];
        __syncthreads();
        for (int k = tid; k < HID / 4; k += 1024)
            ((float4*)xs)[k] = ((const float4*)(X + (size_t)t * HID))[k];
        __syncthreads();

#pragma unroll 1
        for (int e = wv; e < NEXP; e += 16) {
            const float* wr = W + (size_t)e * HID + ln * 4;
            const float* xp = xs + ln * 4;
            float4 w4[8];
#pragma unroll
            for (int j = 0; j < 8; ++j) w4[j] = *(const float4*)(wr + j * 256);
            double a0 = 0.0, a1 = 0.0;
#pragma unroll
            for (int j = 0; j < 8; ++j) {
                a0 = fma((double)xp[j * 256 + 0], (double)w4[j].x, a0);
                a1 = fma((double)xp[j * 256 + 1], (double)w4[j].y, a1);
                a0 = fma((double)xp[j * 256 + 2], (double)w4[j].z, a0);
                a1 = fma((double)xp[j * 256 + 3], (double)w4[j].w, a1);
            }
            double a = a0 + a1;
#pragma unroll
            for (int off = 32; off > 0; off >>= 1) a += __shfl_down(a, off);
            if (ln == 0) ld[e] = a;
        }
        __syncthreads();

        if (tid == 0) {
            double g[NGRP];
#pragma unroll
            for (int gi = 0; gi < NGRP; ++gi) {
                double mx = ld[gi * EPG];
                for (int j = 1; j < EPG; ++j) {
                    const double v = ld[gi * EPG + j];
                    if (v > mx) mx = v;
                }
                g[gi] = mx;
            }
            int gmask = 0;
#pragma unroll
            for (int p = 0; p < KGRP; ++p) {
                double best = -1.0e300; int bi = 0;
#pragma unroll
                for (int gi = 0; gi < NGRP; ++gi)
                    if (!((gmask >> gi) & 1) && g[gi] > best) { best = g[gi]; bi = gi; }
                gmask |= 1 << bi;
            }
            double mall = g[0];
#pragma unroll
            for (int gi = 1; gi < NGRP; ++gi) if (g[gi] > mall) mall = g[gi];
            float denom = 0.f;
            for (int e = 0; e < NEXP; ++e)
                denom += expf((float)(ld[e] - mall));
            const float invd = 1.0f / denom;

            int ch[KTOP];
            for (int p = 0; p < KTOP; ++p) {
                double best = -1.0e300; int bi = 0;
                for (int e = 0; e < NEXP; ++e) {
                    if (!((gmask >> (e / EPG)) & 1)) continue;
                    bool used = false;
#pragma unroll
                    for (int q = 0; q < KTOP; ++q)
                        if (q < p && ch[q] == e) used = true;
                    if (!used && ld[e] > best) { best = ld[e]; bi = e; }
                }
                ch[p] = bi;
                out[(size_t)t * KTOP + p] = (float)bi;
                out[(size_t)T_TOKENS * KTOP + (size_t)t * KTOP + p] =
                    expf((float)(best - mall)) * invd * 16.0f;
            }
        }
        __syncthreads();
    }
}

// ---- aux loss: reduce partials ----------------------------------------------
__global__ __launch_bounds__(256)
void moe_gate_aux(const float* __restrict__ piPart,
                  const unsigned int* __restrict__ histPart,
                  float* __restrict__ out)
{
    __shared__ double buf[NEXP];
    const int tid = threadIdx.x;
    if (tid < NEXP) {
        const float* pp = piPart + (size_t)tid * NBLK;
        const unsigned int* hp = histPart + (size_t)tid * NBLK;
        float s = 0.f;
        unsigned c = 0;
#pragma unroll 8
        for (int b = 0; b < NBLK; ++b) { s += pp[b]; c += hp[b]; }
        buf[tid] = (double)s * (double)c;
    }
    __syncthreads();
    if (tid == 0) {
        double s = 0.0;
        for (int e = 0; e < NEXP; ++e) s += buf[e];
        const double aux = s * (0.001 * (double)NEXP) /
                           ((double)T_TOKENS * (double)T_TOKENS * (double)KTOP);
        out[(size_t)T_TOKENS * KTOP * 2] = (float)aux;
    }
}

extern "C" void kernel_launch(void* const* d_in, const int* in_sizes, int n_in,
                              void* d_out, int out_size, void* d_ws, size_t ws_size,
                              hipStream_t stream)
{
    const float* X = (const float*)d_in[0];   // [16384, 2048]
    const float* W = (const float*)d_in[1];   // [160, 2048]
    float* out = (float*)d_out;               // [98304 idx][98304 wgt][1 aux]

    char* ws = (char*)d_ws;
    short* wpk = (short*)ws;                                    // 1,310,720 B
    float* glog = (float*)(ws + 1310720);                       // 10,485,760 B
    float* piPart = (float*)(ws + 11796480);                    // 163,840 B
    unsigned int* histPart = (unsigned int*)(ws + 11960320);    // 163,840 B
    unsigned int* flagCnt  = (unsigned int*)(ws + 12124160);    // 16 B
    unsigned int* flagList = (unsigned int*)(ws + 12124176);    // 64 KB

    hipMemsetAsync(flagCnt, 0, 16, stream);
    pack_w<<<160, 256, 0, stream>>>(W, wpk);
    moe_gemm<<<NBLK, 512, 0, stream>>>(X, wpk, glog);
    moe_epi<<<NBLK, 512, 0, stream>>>(glog, out, piPart, histPart, flagCnt, flagList);
    moe_gate_fixup<<<512, 1024, 0, stream>>>(X, W, out, flagCnt, flagList);
    moe_gate_aux<<<1, 256, 0, stream>>>(piPart, histPart, out);
}